// Round 11
// baseline (162.787 us; speedup 1.0000x reference)
//
#include <hip/hip_runtime.h>
#include <math.h>

namespace {
constexpr int B_ = 32, S_ = 1024, D_ = 256, N_ = 32, C_ = 64;
constexpr int NC_ = N_ * C_;  // 2048
constexpr int XP_ = 16;       // xsum partials / s-chunks per b

typedef __bf16 bf16x8 __attribute__((ext_vector_type(8)));
typedef __bf16 bf16x4 __attribute__((ext_vector_type(4)));
typedef float floatx4 __attribute__((ext_vector_type(4)));

constexpr int XS_ = 264;  // x_lds row stride
constexpr int CS_ = 72;   // c_T row stride (s 64 + 8 pad)
}  // namespace

// K1: per (b, s-chunk): ONE float4 sweep over x -> bf16 staging + xsum partial.
extern "C" __global__ __launch_bounds__(256) void k_stage(
    const float* __restrict__ x, float* __restrict__ xsum_part,
    __bf16* __restrict__ xb_ws) {
  __shared__ float red[1024];
  const int b = blockIdx.x, sb = blockIdx.y, t = threadIdx.x;
  const float* xb = x + ((size_t)b * S_ + sb * 64) * D_;
  __bf16* xo = xb_ws + ((size_t)(b * XP_ + sb)) * (64 * D_);

  float xp[4] = {0.f, 0.f, 0.f, 0.f};
  #pragma unroll
  for (int i = 0; i < 16; ++i) {
    int pos = i * 1024 + t * 4;   // row advances; col = (t&63)*4 fixed
    float4 f = *(const float4*)(xb + pos);
    bf16x4 p4;
    p4[0] = (__bf16)f.x; p4[1] = (__bf16)f.y;
    p4[2] = (__bf16)f.z; p4[3] = (__bf16)f.w;
    *(bf16x4*)(xo + pos) = p4;
    xp[0] += f.x; xp[1] += f.y; xp[2] += f.z; xp[3] += f.w;
  }
  const int w = t >> 6, col = (t & 63) * 4;
  #pragma unroll
  for (int k = 0; k < 4; ++k) red[w * 256 + col + k] = xp[k];
  __syncthreads();
  xsum_part[((size_t)b * XP_ + sb) * D_ + t] =
      red[t] + red[256 + t] + red[512 + t] + red[768 + t];
}

// K2 (small chain) per (n,b) -- grid ordered (N, B) so all blocks sharing an
// n-slice of W land on the same XCD (linear idx = n + b*32, 32%8==0 -> XCD=n%8):
// W stays L2-resident across the 32 b-blocks.
//   zloc[d] = sum_p z[...]; s[c] = scale * zloc@W[n]; v = squash(s)
//   final: v -> vout;  else: t = W[n]@v (+= old if accum) -> fp32 + bf16 hi/lo
//   yzero: zero this block's 256-float row of the NEXT pass's y accumulator.
extern "C" __global__ __launch_bounds__(256) void k_small(
    const float* __restrict__ z, const float* __restrict__ W,
    float* __restrict__ t_fp, __bf16* __restrict__ t_bhi,
    __bf16* __restrict__ t_blo, float* __restrict__ vout,
    float* __restrict__ yzero,
    int P, int zb, int zp, int zn, float scale, int accum, int final_) {
  __shared__ float zloc[256];
  __shared__ float sq_red[4][64];
  __shared__ float v_lds[64];
  const int n = blockIdx.x, b = blockIdx.y, t = threadIdx.x;

  float a = 0.f;
  for (int p = 0; p < P; ++p) a += z[(size_t)b * zb + (size_t)p * zp + n * zn + t];
  zloc[t] = a;
  if (yzero) yzero[((size_t)b * N_ + n) * D_ + t] = 0.f;
  __syncthreads();

  const int c = t & 63, dq = t >> 6;
  const float* Wn = W + (size_t)n * (D_ * C_);
  float s = 0.f;
  #pragma unroll 8
  for (int dd = 0; dd < 64; ++dd) {
    int d = dq * 64 + dd;
    s += zloc[d] * Wn[d * 64 + c];
  }
  sq_red[dq][c] = s;
  __syncthreads();

  if (t < 64) {
    float sc = (sq_red[0][t] + sq_red[1][t] + sq_red[2][t] + sq_red[3][t]) * scale;
    float sq = sc * sc;
    #pragma unroll
    for (int m = 1; m <= 32; m <<= 1) sq += __shfl_xor(sq, m);
    float scl = sq / ((1.f + sq) * sqrtf(sq + 1e-8f));
    float v = sc * scl;
    v_lds[t] = v;
    if (final_) vout[(size_t)b * NC_ + n * 64 + t] = v;
  }
  __syncthreads();

  if (!final_) {
    const float4* W4 = (const float4*)Wn + t * 16;
    float acc = 0.f;
    #pragma unroll
    for (int q = 0; q < 16; ++q) {
      float4 wv = W4[q];
      acc += wv.x * v_lds[q * 4] + wv.y * v_lds[q * 4 + 1] +
             wv.z * v_lds[q * 4 + 2] + wv.w * v_lds[q * 4 + 3];
    }
    size_t idx = ((size_t)b * N_ + n) * D_ + t;
    float tf = acc + (accum ? t_fp[idx] : 0.f);
    t_fp[idx] = tf;
    __bf16 hi = (__bf16)tf;
    t_bhi[idx] = hi;
    t_blo[idx] = (__bf16)(tf - (float)hi);
  }
}

// K3 (routing pass) per (b, s-chunk of 64):
//   agr[s,n] = x.t via MFMA (t bf16 hi+lo, fragments direct from global/L2;
//   grid (b,ch) puts all 16 ch-blocks of a b on XCD b%8 -> t is L2-hot)
//   -> softmax over n -> y[b,n,d] += c^T @ x via MFMA, fp32 atomics.
extern "C" __global__ __launch_bounds__(256) void k_pass(
    const __bf16* __restrict__ xb_ws, const __bf16* __restrict__ t_bhi,
    const __bf16* __restrict__ t_blo, float* __restrict__ y) {
  __shared__ __align__(16) __bf16 x_lds[64 * XS_];  // 33,792 B
  __shared__ __align__(16) __bf16 c_Th[N_ * CS_];   //  4,608 B
  __shared__ __align__(16) __bf16 c_Tl[N_ * CS_];   //  4,608 B  (total 43,008)
  const int b = blockIdx.x, ch = blockIdx.y;
  const int t = threadIdx.x, w = t >> 6, lane = t & 63;
  const int quad = lane >> 4, l16 = lane & 15;

  // stage x (already bf16 in ws)
  const __bf16* xsrc = xb_ws + ((size_t)(b * XP_ + ch)) * (64 * D_);
  #pragma unroll
  for (int e = 0; e < 8; ++e) {
    int idx = e * 2048 + t * 8;
    int row = idx >> 8, col = idx & 255;
    *(uint4*)(x_lds + row * XS_ + col) = *(const uint4*)(xsrc + idx);
  }
  __syncthreads();

  // agreement GEMM: A=t (m=n), B=x (n'=s), K=256; wave w owns s-tile w*16.
  // t fragments direct from global (L2-hot).
  const __bf16* tb_h = t_bhi + (size_t)b * 8192;
  const __bf16* tb_l = t_blo + (size_t)b * 8192;
  floatx4 acc[2];
  acc[0] = (floatx4){0.f, 0.f, 0.f, 0.f};
  acc[1] = (floatx4){0.f, 0.f, 0.f, 0.f};
  const int sbase = w * 16;
  #pragma unroll
  for (int k0 = 0; k0 < 256; k0 += 32) {
    int ks = k0 + quad * 8;
    bf16x8 bfrag = *(const bf16x8*)(x_lds + (sbase + l16) * XS_ + ks);
    #pragma unroll
    for (int i = 0; i < 2; ++i) {
      bf16x8 ah = *(const bf16x8*)(tb_h + (i * 16 + l16) * 256 + ks);
      bf16x8 al = *(const bf16x8*)(tb_l + (i * 16 + l16) * 256 + ks);
      acc[i] = __builtin_amdgcn_mfma_f32_16x16x32_bf16(ah, bfrag, acc[i], 0, 0, 0);
      acc[i] = __builtin_amdgcn_mfma_f32_16x16x32_bf16(al, bfrag, acc[i], 0, 0, 0);
    }
  }
  // softmax over n for s = sbase + l16
  float mx = -1e30f;
  #pragma unroll
  for (int i = 0; i < 2; ++i)
    #pragma unroll
    for (int r = 0; r < 4; ++r) mx = fmaxf(mx, acc[i][r]);
  mx = fmaxf(mx, __shfl_xor(mx, 16));
  mx = fmaxf(mx, __shfl_xor(mx, 32));
  float e_[2][4];
  float ss = 0.f;
  #pragma unroll
  for (int i = 0; i < 2; ++i)
    #pragma unroll
    for (int r = 0; r < 4; ++r) { e_[i][r] = __expf(acc[i][r] - mx); ss += e_[i][r]; }
  ss += __shfl_xor(ss, 16);
  ss += __shfl_xor(ss, 32);
  float inv = 1.f / ss;
  #pragma unroll
  for (int i = 0; i < 2; ++i)
    #pragma unroll
    for (int r = 0; r < 4; ++r) {
      float cv = e_[i][r] * inv;
      __bf16 chi = (__bf16)cv;
      int o = (i * 16 + quad * 4 + r) * CS_ + sbase + l16;
      c_Th[o] = chi;
      c_Tl[o] = (__bf16)(cv - (float)chi);
    }
  __syncthreads();

  // y GEMM: y[n,d] += c^T @ x; wave w owns d-range w*64
  floatx4 acc2[2][4];
  #pragma unroll
  for (int i = 0; i < 2; ++i)
    #pragma unroll
    for (int dt = 0; dt < 4; ++dt) acc2[i][dt] = (floatx4){0.f, 0.f, 0.f, 0.f};
  const int dbase = w * 64;
  #pragma unroll
  for (int k0 = 0; k0 < 64; k0 += 32) {
    int ks = k0 + quad * 8;
    bf16x8 ah[2], al[2];
    #pragma unroll
    for (int i = 0; i < 2; ++i) {
      ah[i] = *(const bf16x8*)(c_Th + (i * 16 + l16) * CS_ + ks);
      al[i] = *(const bf16x8*)(c_Tl + (i * 16 + l16) * CS_ + ks);
    }
    #pragma unroll
    for (int dt = 0; dt < 4; ++dt) {
      bf16x8 bfr;
      #pragma unroll
      for (int j8 = 0; j8 < 8; ++j8)
        bfr[j8] = x_lds[(ks + j8) * XS_ + dbase + dt * 16 + l16];
      #pragma unroll
      for (int i = 0; i < 2; ++i) {
        acc2[i][dt] = __builtin_amdgcn_mfma_f32_16x16x32_bf16(ah[i], bfr, acc2[i][dt], 0, 0, 0);
        acc2[i][dt] = __builtin_amdgcn_mfma_f32_16x16x32_bf16(al[i], bfr, acc2[i][dt], 0, 0, 0);
      }
    }
  }
  #pragma unroll
  for (int i = 0; i < 2; ++i)
    #pragma unroll
    for (int dt = 0; dt < 4; ++dt)
      #pragma unroll
      for (int r = 0; r < 4; ++r) {
        int n = i * 16 + quad * 4 + r;
        int d = dbase + dt * 16 + l16;
        atomicAdd(&y[((size_t)b * N_ + n) * D_ + d], acc2[i][dt][r]);
      }
}

extern "C" void kernel_launch(void* const* d_in, const int* in_sizes, int n_in,
                              void* d_out, int out_size, void* d_ws, size_t ws_size,
                              hipStream_t stream) {
  const float* x = (const float*)d_in[0];   // [B,S,D] fp32
  const float* W = (const float*)d_in[1];   // [N,D,C] fp32
  float* out = (float*)d_out;               // [B,N,C] fp32

  // ws (~21 MB): [xb_ws 16M | xsum_part 512K | y1 1M | y2 1M | t_fp 1M | t_bhi 512K | t_blo 512K]
  char* ws = (char*)d_ws;
  __bf16* xb_ws = (__bf16*)ws;
  float* xsum_part = (float*)(ws + 16777216);
  float* y1 = (float*)(ws + 16777216 + 524288);
  float* y2 = y1 + B_ * N_ * D_;
  float* t_fp = y2 + B_ * N_ * D_;
  __bf16* t_bhi = (__bf16*)(t_fp + B_ * N_ * D_);
  __bf16* t_blo = t_bhi + B_ * N_ * D_;

  // 1) single-sweep stage: x -> bf16 ws + xsum partials
  k_stage<<<dim3(B_, XP_), 256, 0, stream>>>(x, xsum_part, xb_ws);

  // 2) iter 0: s1=(1/N)xsum@W -> v1 -> t1; zero y1   (grid = (n, b))
  k_small<<<dim3(N_, B_), 256, 0, stream>>>(
      xsum_part, W, t_fp, t_bhi, t_blo, nullptr, y1,
      XP_, XP_ * D_, D_, 0, 1.f / 32.f, 0, 0);

  // 3) pass 1: y1 += c2^T @ x
  k_pass<<<dim3(B_, XP_), 256, 0, stream>>>(xb_ws, t_bhi, t_blo, y1);

  // 4) s2=y1@W -> v2 -> t12 = t1 + W@v2; zero y2
  k_small<<<dim3(N_, B_), 256, 0, stream>>>(
      y1, W, t_fp, t_bhi, t_blo, nullptr, y2,
      1, N_ * D_, 0, D_, 1.f, 1, 0);

  // 5) pass 2: y2 += c3^T @ x
  k_pass<<<dim3(B_, XP_), 256, 0, stream>>>(xb_ws, t_bhi, t_blo, y2);

  // 6) s3=y2@W -> squash -> out
  k_small<<<dim3(N_, B_), 256, 0, stream>>>(
      y2, W, t_fp, t_bhi, t_blo, out, nullptr,
      1, N_ * D_, 0, D_, 1.f, 0, 1);
}